// Round 10
// baseline (241.509 us; speedup 1.0000x reference)
//
#include <hip/hip_runtime.h>

namespace {

constexpr int B_ = 16;
constexpr int T_ = 32;
constexpr int N_ = 6000;
constexpr int K_ = 32;
constexpr int D_ = 8;
constexpr float EPS_ = 1e-8f;
constexpr float PW_  = 0.1f;

constexpr int CH = 256;                  // n-chunk per block
constexpr int NB = 24;                   // ceil(6000/256)
constexpr int TS = 4;                    // t-splits per (b,chunk)
constexpr int TC = T_ / TS;              // 8 timesteps per block == waves per block

// workspace layout (float offsets)
constexpr int FTY_OFF = 0;                         // B*T*K*D = 131072
constexpr int SYY_OFF = FTY_OFF + B_*T_*K_*D_;     // B*T*D
constexpr int SY_OFF  = SYY_OFF + B_*T_*D_;        // B*T*D
constexpr int FTF_OFF = SY_OFF  + B_*T_*D_;        // B*K*K
constexpr int SP_OFF  = FTF_OFF + B_*K_*K_;        // B*K
constexpr int ZERO_FLOATS = SP_OFF + B_*K_;
constexpr int INV_OFF = ZERO_FLOATS;               // B*K*K (fully overwritten)

typedef short  bf16x8 __attribute__((ext_vector_type(8)));
typedef float  f32x4  __attribute__((ext_vector_type(4)));

// fp32 -> bf16 (RNE) as raw bits
__device__ inline short f2bf(float v) {
  unsigned u = __float_as_uint(v);
  unsigned r = (u + 0x7fffu + ((u >> 16) & 1u)) >> 16;
  return (short)r;
}

// async global->LDS, 16B per lane. dst must be the WAVE-uniform base; HW adds lane*16.
__device__ inline void gload_lds16(const float* g, float* l) {
  __builtin_amdgcn_global_load_lds(
      (const __attribute__((address_space(1))) void*)g,
      (__attribute__((address_space(3))) void*)l, 16, 0, 0);
}

// ---------------------------------------------------------------------------
// stats: grid = B*NB*TS blocks x 512. Block owns (b, 256-row chunk, 8 t's);
// wave w owns t = t0+w entirely (own y LDS slot, own MFMA, own atomics) ->
// no per-t barriers. Fty via bf16 MFMA 16x16x32 (fp32 acc); FtF/Sp fp32 by
// ts==0 blocks; Syy/Sy free-ride on B-fragment loads.
// ---------------------------------------------------------------------------
__global__ __launch_bounds__(512)
void stats_kernel(const float* __restrict__ preds,
                  const float* __restrict__ y,
                  float* __restrict__ ws)
{
  __shared__ float p_lds[CH * K_];       // 32 KB  [n][k]
  __shared__ float y_lds[TC][CH * D_];   // 64 KB  per-wave slot [n*8+d]
  __shared__ float red[8 * 288];         //  9 KB  FtF cross-wave reduce

  const int tid  = threadIdx.x;
  const int w    = tid >> 6;
  const int lane = tid & 63;

  const int bid = blockIdx.x;
  const int ts  = bid & (TS - 1);
  const int c   = (bid >> 2) % NB;
  const int bb  = bid / (TS * NB);
  const int n0  = c * CH;
  const int rows_valid = min(CH, N_ - n0);
  const int t0  = ts * TC;

  // ---- stage preds chunk into LDS (async, zero-pad past N) ----
  const float* pb = preds + ((size_t)bb * N_ + n0) * K_;
  const int pvalid4 = rows_valid * 8;          // float4 count (rows*32/4)
  #pragma unroll
  for (int i = 0; i < 4; ++i) {
    const int idx = i * 512 + tid;             // float4 index in chunk
    if (idx < pvalid4) gload_lds16(pb + (size_t)idx * 4, p_lds + i * 2048 + w * 256);
    else *reinterpret_cast<float4*>(p_lds + idx * 4) = make_float4(0.f, 0.f, 0.f, 0.f);
  }

  // ---- each wave stages its OWN t's y into its OWN slot ----
  const int t = t0 + w;
  float* slot = &y_lds[w][0];
  const int yvalid4 = rows_valid * 2;          // float4 count (rows*8/4)
  const float* ysrc = y + (((size_t)bb * T_ + t) * N_ + n0) * D_;
  #pragma unroll
  for (int i = 0; i < 8; ++i) {
    const int idx4 = i * 64 + lane;
    if (idx4 < yvalid4) gload_lds16(ysrc + (size_t)idx4 * 4, slot + i * 256);
    else *reinterpret_cast<float4*>(slot + idx4 * 4) = make_float4(0.f, 0.f, 0.f, 0.f);
  }

  __syncthreads();   // p_lds + all y slots ready (barrier drains vmcnt/lgkmcnt)

  // ---- FtF + Sp (ts==0 blocks only; block-uniform branch; fp32 exact) ----
  if (ts == 0) {
    const int k    = lane & 31;
    const int nsub = lane >> 5;
    float a2[K_];
    #pragma unroll
    for (int j = 0; j < K_; ++j) a2[j] = 0.f;
    float sp = 0.f;
    for (int it = 0; it < CH / 16; ++it) {
      const int nloc = it * 16 + w * 2 + nsub;
      const float pk = p_lds[nloc * K_ + k];
      sp += pk;
      const float4* row = reinterpret_cast<const float4*>(p_lds + nloc * K_);
      #pragma unroll
      for (int j4 = 0; j4 < 8; ++j4) {
        const float4 r = row[j4];
        a2[j4*4+0] = fmaf(pk, r.x, a2[j4*4+0]);
        a2[j4*4+1] = fmaf(pk, r.y, a2[j4*4+1]);
        a2[j4*4+2] = fmaf(pk, r.z, a2[j4*4+2]);
        a2[j4*4+3] = fmaf(pk, r.w, a2[j4*4+3]);
      }
    }
    #pragma unroll
    for (int j = 0; j < K_; ++j) a2[j] += __shfl_down(a2[j], 32);
    sp += __shfl_down(sp, 32);

    float* ftf = ws + FTF_OFF + bb * (K_*K_);
    #pragma unroll
    for (int g = 0; g < 4; ++g) {
      if (lane < 32) {
        #pragma unroll
        for (int j = 0; j < 8; ++j) red[w*288 + k*9 + j] = a2[g*8 + j];
      }
      __syncthreads();
      if (tid < 256) {
        const int kk = tid >> 3, jj = tid & 7;
        float s = 0.f;
        #pragma unroll
        for (int ww = 0; ww < 8; ++ww) s += red[ww*288 + kk*9 + jj];
        atomicAdd(&ftf[kk*K_ + g*8 + jj], s);
      }
      __syncthreads();
    }
    if (lane < 32) red[w*288 + k*9] = sp;
    __syncthreads();
    if (tid < 32) {
      float s = 0.f;
      #pragma unroll
      for (int ww = 0; ww < 8; ++ww) s += red[ww*288 + tid*9];
      atomicAdd(&ws[SP_OFF + bb*K_ + tid], s);
    }
    // no trailing barrier needed: waves go independent from here
  }

  // ---- A-fragments (P^T), built once per block, bf16 in registers ----
  // mfma_f32_16x16x32_bf16: A[16m x 32k]: lane-> m = lane&15, k = (lane>>4)*8+j
  // Our mapping: m -> Fty-k (mt*16 + mrow), contraction k -> chunk row n.
  const int mrow = lane & 15;
  const int g8   = (lane >> 4) * 8;
  bf16x8 afrag[8][2];
  #pragma unroll
  for (int nt = 0; nt < 8; ++nt) {
    #pragma unroll
    for (int mt = 0; mt < 2; ++mt) {
      bf16x8 f;
      #pragma unroll
      for (int j = 0; j < 8; ++j)
        f[j] = f2bf(p_lds[(nt*32 + g8 + j) * K_ + mt*16 + mrow]);
      afrag[nt][mt] = f;
    }
  }

  // ---- per-wave t-work: B-frags + MFMA + Syy/Sy free-ride ----
  // B[32k x 16n]: lane-> n = lane&15 (our d, cols 8..15 fed zeros),
  //               k = (lane>>4)*8+j (our chunk row within the 32-tile)
  const int dcol = lane & 15;
  const bool dok = dcol < 8;
  f32x4 acc0 = {0.f, 0.f, 0.f, 0.f};
  f32x4 acc1 = {0.f, 0.f, 0.f, 0.f};
  float syy = 0.f, sy = 0.f;

  #pragma unroll
  for (int nt = 0; nt < 8; ++nt) {
    bf16x8 bfr;
    #pragma unroll
    for (int j = 0; j < 8; ++j) {
      const float v = dok ? slot[(nt*32 + g8 + j) * D_ + dcol] : 0.f;
      syy = fmaf(v, v, syy);
      sy += v;
      bfr[j] = f2bf(v);
    }
    acc0 = __builtin_amdgcn_mfma_f32_16x16x32_bf16(afrag[nt][0], bfr, acc0, 0, 0, 0);
    acc1 = __builtin_amdgcn_mfma_f32_16x16x32_bf16(afrag[nt][1], bfr, acc1, 0, 0, 0);
  }

  // Syy/Sy: each (n,d) was read by exactly one lane (lanes sharing dcol are
  // lane, lane+16, lane+32, lane+48) -> 2-step shuffle reduce, then atomics.
  syy += __shfl_down(syy, 32);  sy += __shfl_down(sy, 32);
  syy += __shfl_down(syy, 16);  sy += __shfl_down(sy, 16);
  if (lane < 8) {
    atomicAdd(&ws[SYY_OFF + ((size_t)bb*T_ + t)*D_ + lane], syy);
    atomicAdd(&ws[SY_OFF  + ((size_t)bb*T_ + t)*D_ + lane], sy);
  }

  // Fty: C/D layout col = lane&15 (d), row = (lane>>4)*4 + reg  [m89 verified]
  if (dok) {
    float* fty = ws + FTY_OFF + (size_t)(bb*T_ + t) * (K_*D_);
    #pragma unroll
    for (int r = 0; r < 4; ++r) {
      const int row = (lane >> 4) * 4 + r;
      atomicAdd(&fty[row        * D_ + dcol], acc0[r]);
      atomicAdd(&fty[(16 + row) * D_ + dcol], acc1[r]);
    }
  }
}

// ---------------------------------------------------------------------------
// Register-resident Gauss-Jordan inverse of (FtF + EPS*I), one 64-lane wave
// per batch; lane owns one column of [A | I]; zero barriers, zero LDS.
// SPD + strongly diagonally dominant (diag ~6000) -> no pivoting.
// ---------------------------------------------------------------------------
__global__ __launch_bounds__(64)
void invert_kernel(float* __restrict__ ws)
{
  const int b = blockIdx.x;
  const int lane = threadIdx.x;
  const float* A = ws + FTF_OFF + b * (K_*K_);

  float m[32];
  #pragma unroll
  for (int r = 0; r < 32; ++r) {
    if (lane < 32) m[r] = A[r*32 + lane] + (r == lane ? EPS_ : 0.f);
    else           m[r] = ((lane - 32) == r) ? 1.f : 0.f;
  }

  #pragma unroll
  for (int p = 0; p < 32; ++p) {
    const float ip = 1.0f / __shfl(m[p], p);
    m[p] *= ip;
    #pragma unroll
    for (int r = 0; r < 32; ++r) {
      if (r == p) continue;
      const float f = __shfl(m[r], p);
      m[r] = fmaf(-f, m[p], m[r]);
    }
  }

  float* out = ws + INV_OFF + b * (K_*K_);
  #pragma unroll
  for (int r = 0; r < 32; ++r)
    if (lane >= 32) out[r*32 + (lane - 32)] = m[r];
}

// ---------------------------------------------------------------------------
// finish per (b,t): beta = inv @ Fty;
// ss_res[d] = Syy - sum_k Fty*beta - EPS*|beta|^2  (exact identity, no gamma)
// ---------------------------------------------------------------------------
__global__ __launch_bounds__(256)
void finish_kernel(const float* __restrict__ ws,
                   const float* __restrict__ imp,
                   float* __restrict__ out)
{
  const int bt = blockIdx.x;
  const int b  = bt / T_;
  const int t  = bt - b * T_;
  const int tid = threadIdx.x;

  __shared__ float sInv[32][33];
  __shared__ float sFty[256];
  __shared__ float sRed[32][8];
  __shared__ float sW[8];

  for (int idx = tid; idx < 1024; idx += 256)
    sInv[idx >> 5][idx & 31] = ws[INV_OFF + b*(K_*K_) + idx];
  sFty[tid] = ws[FTY_OFF + (size_t)bt * 256 + tid];
  __syncthreads();

  const int kk = tid >> 3, dd = tid & 7;
  float beta = 0.f;
  #pragma unroll
  for (int j = 0; j < 32; ++j) beta = fmaf(sInv[kk][j], sFty[j*8 + dd], beta);
  const float fty = sFty[kk*8 + dd];
  sRed[kk][dd] = fty * beta + EPS_ * beta * beta;
  __syncthreads();

  if (tid < 8) {
    float dots = 0.f;
    #pragma unroll
    for (int k2 = 0; k2 < 32; ++k2) dots += sRed[k2][tid];
    const float syy = ws[SYY_OFF + bt*D_ + tid];
    const float syv = ws[SY_OFF  + bt*D_ + tid];
    const float ss_res = syy - dots;
    const float ss_tot = syy - syv*syv*(1.0f/N_) + EPS_;
    sW[tid] = (1.f - ss_res/ss_tot) * imp[tid];
  }
  __syncthreads();

  if (tid == 0) {
    float wr2 = 0.f;
    #pragma unroll
    for (int d = 0; d < 8; ++d) wr2 += sW[d];
    atomicAdd(out, -wr2 * powf(0.9f, (float)t) * (1.0f / (T_ * B_)));
  }
}

// ---------------------------------------------------------------------------
// Correlation penalty per batch.
// ---------------------------------------------------------------------------
__global__ __launch_bounds__(256)
void corr_kernel(const float* __restrict__ ws, float* __restrict__ out)
{
  const int b = blockIdx.x;
  const int tid = threadIdx.x;
  __shared__ float sC[32][33];
  __shared__ float sStd[32];

  for (int idx = tid; idx < 1024; idx += 256) {
    const int r = idx >> 5, c2 = idx & 31;
    const float cov = ws[FTF_OFF + b*(K_*K_) + idx]
                    - ws[SP_OFF + b*K_ + r] * ws[SP_OFF + b*K_ + c2] * (1.0f/N_);
    sC[r][c2] = cov;
  }
  __syncthreads();
  if (tid < 32) sStd[tid] = sqrtf(sC[tid][tid]);
  __syncthreads();

  float acc = 0.f;
  for (int idx = tid; idx < 1024; idx += 256) {
    const int r = idx >> 5, c2 = idx & 31;
    if (r != c2) {
      const float cr = sC[r][c2] / (sStd[r] * sStd[c2]);
      acc = fmaf(cr, cr, acc);
    }
  }
  acc += __shfl_down(acc, 32);
  acc += __shfl_down(acc, 16);
  acc += __shfl_down(acc, 8);
  acc += __shfl_down(acc, 4);
  acc += __shfl_down(acc, 2);
  acc += __shfl_down(acc, 1);
  if ((tid & 63) == 0) atomicAdd(out, acc * (PW_ / B_));
}

} // namespace

extern "C" void kernel_launch(void* const* d_in, const int* in_sizes, int n_in,
                              void* d_out, int out_size, void* d_ws, size_t ws_size,
                              hipStream_t stream)
{
  const float* preds = (const float*)d_in[0];
  const float* y     = (const float*)d_in[1];
  const float* imp   = (const float*)d_in[2];
  float* out = (float*)d_out;
  float* ws  = (float*)d_ws;

  hipMemsetAsync(ws, 0, (size_t)ZERO_FLOATS * sizeof(float), stream);
  hipMemsetAsync(out, 0, sizeof(float), stream);

  stats_kernel<<<B_ * NB * TS, 512, 0, stream>>>(preds, y, ws);
  invert_kernel<<<B_, 64, 0, stream>>>(ws);
  finish_kernel<<<B_ * T_, 256, 0, stream>>>(ws, imp, out);
  corr_kernel<<<B_, 256, 0, stream>>>(ws, out);
}